// Round 3
// baseline (381.812 us; speedup 1.0000x reference)
//
#include <hip/hip_runtime.h>
#include <hip/hip_cooperative_groups.h>

namespace cg = cooperative_groups;

#define Bn 4
#define Qn 128
#define Kn 1024
#define Dn 512   // DQ = DK = DV = 512
#define Hn 256

// tanh(x) = 1 - 2/(1 + e^{2x}).  Inf-safe: e->inf => rcp(inf)=0 => 1.
__device__ __forceinline__ float fast_tanh(float x) {
    float e = __expf(2.0f * x);
    return 1.0f - 2.0f * __builtin_amdgcn_rcpf(1.0f + e);
}

// ---------------------------------------------------------------------------
// Single cooperative kernel, 256 blocks x 512 threads (1 block/CU, 8 waves).
// Phases separated by grid.sync():
//   P0: zero out + rowsum (no escores zeroing needed anymore)
//   P1: projections GEMM, 576 jobs = mt(72) x nt(4) x kc(2 split-K halves),
//       64x64 tile, BK=64, reg->LDS double-buffer, 8-wave intra-block split-K
//       (waves 0-3: kk 0..31, waves 4-7: kk 32..63), LDS merge. No vlen
//       early-out (uniform control flow); extra rows are cheap and harmless.
//   P2: scores, 512 jobs = b(4) x q-half(2: 64 q) x kt(64: 16 k). Wave =
//       (16 kloc x 4 hq) lanes, 8 q-rows per wave from a 64-row LDS q-panel:
//       each kv/wv fragment load amortizes over 8 q-rows -> LDS-pipe cost
//       ~0.06 cyc/element (was 0.14). e = exp(score), atomic rowsum.
//   P3: AV + fused normalize, 256 jobs = b(4) x qt(16: 8q) x kc(4: 256k).
//       escores staged with per-component k<vlen guard (masked k -> 0), fully
//       masked chunks skipped; atomicAdd of acc*rcp(rowsum) into zeroed out.
// LDS: union, max phase = score (83200 B) -> 1 block/CU (fits 160 KB pool).
// ---------------------------------------------------------------------------
__global__ __launch_bounds__(512) void fused_kernel(
    const float* __restrict__ queries, const float* __restrict__ keys,
    const float* __restrict__ values, const int* __restrict__ valid_lens,
    const float* __restrict__ Wq, const float* __restrict__ Wk,
    const float* __restrict__ wv,
    float* __restrict__ proj0, float* __restrict__ proj1,
    float* __restrict__ escores, float* __restrict__ rowsum,
    float* __restrict__ out)
{
    __shared__ float smem[20800];   // 83200 B
    const int t = threadIdx.x;
    const int blk = blockIdx.x;
    cg::grid_group grid = cg::this_grid();

    // ---- Phase 0: zero out + rowsum --------------------------------------
    {
        const int gid = blk * 512 + t;
        float4 z = {0.f, 0.f, 0.f, 0.f};
        if (gid < (Bn * Qn * Dn) / 4) ((float4*)out)[gid] = z;
        if (gid < (Bn * Qn) / 4)      ((float4*)rowsum)[gid] = z;
    }

    // ---- Phase 1: projections --------------------------------------------
    {
        float* s_a = smem;              // [64][68]
        float* s_b = smem + 64 * 68;    // [64][64]
        const int lrow = t >> 4, lc4 = t & 15;      // staging coords
        const int tt = t & 255, kh = t >> 8;        // compute coords
        const int trow = tt >> 4, tcol = tt & 15;
        const int kklo = kh << 5;

        for (int job = blk; job < 576; job += 256) {
            const int kc = job & 1;
            const int nt = (job >> 1) & 3;
            const int mt = job >> 3;                // 0..71
            const float *Asrc, *W; int m0, drow;
            if (mt < 8) { m0 = mt * 64;       drow = m0;       Asrc = queries; W = Wq; }
            else        { m0 = (mt - 8) * 64; drow = 512 + m0; Asrc = keys;    W = Wk; }
            const int n0 = nt * 64;
            const int kb = kc * 256;
            float* Dst = (kc ? proj1 : proj0) + (size_t)drow * Hn;

            float acc[4][4] = {{0.f}};
            float4 ra[2], rb[2];
            #pragma unroll
            for (int i = 0; i < 2; ++i) {
                ra[i] = *(const float4*)(Asrc + (size_t)(m0 + lrow + i * 32) * Dn + kb + lc4 * 4);
                rb[i] = *(const float4*)(W + (size_t)(kb + lrow + i * 32) * Hn + n0 + lc4 * 4);
            }
            for (int kt = 0; kt < 4; ++kt) {
                __syncthreads();
                #pragma unroll
                for (int i = 0; i < 2; ++i) {
                    int row = lrow + i * 32;
                    s_a[(lc4 * 4 + 0) * 68 + row] = ra[i].x;
                    s_a[(lc4 * 4 + 1) * 68 + row] = ra[i].y;
                    s_a[(lc4 * 4 + 2) * 68 + row] = ra[i].z;
                    s_a[(lc4 * 4 + 3) * 68 + row] = ra[i].w;
                    *(float4*)&s_b[row * 64 + lc4 * 4] = rb[i];
                }
                __syncthreads();
                if (kt < 3) {
                    const int d0n = kb + (kt + 1) * 64;
                    #pragma unroll
                    for (int i = 0; i < 2; ++i) {
                        ra[i] = *(const float4*)(Asrc + (size_t)(m0 + lrow + i * 32) * Dn + d0n + lc4 * 4);
                        rb[i] = *(const float4*)(W + (size_t)(d0n + lrow + i * 32) * Hn + n0 + lc4 * 4);
                    }
                }
                #pragma unroll
                for (int kk = 0; kk < 32; ++kk) {
                    float4 a4 = *(const float4*)&s_a[(kklo + kk) * 68 + trow * 4];
                    float4 b4 = *(const float4*)&s_b[(kklo + kk) * 64 + tcol * 4];
                    float a[4] = {a4.x, a4.y, a4.z, a4.w};
                    float b[4] = {b4.x, b4.y, b4.z, b4.w};
                    #pragma unroll
                    for (int i = 0; i < 4; ++i)
                        #pragma unroll
                        for (int j = 0; j < 4; ++j)
                            acc[i][j] += a[i] * b[j];
                }
            }
            // merge k-halves via LDS (s_a region; stride 17 conflict-free)
            __syncthreads();
            float* red = smem;
            if (kh) {
                #pragma unroll
                for (int i = 0; i < 4; ++i)
                    #pragma unroll
                    for (int j = 0; j < 4; ++j)
                        red[tt * 17 + i * 4 + j] = acc[i][j];
            }
            __syncthreads();
            if (!kh) {
                #pragma unroll
                for (int i = 0; i < 4; ++i) {
                    float4 o;
                    o.x = acc[i][0] + red[tt * 17 + i * 4 + 0];
                    o.y = acc[i][1] + red[tt * 17 + i * 4 + 1];
                    o.z = acc[i][2] + red[tt * 17 + i * 4 + 2];
                    o.w = acc[i][3] + red[tt * 17 + i * 4 + 3];
                    *(float4*)(Dst + (size_t)(trow * 4 + i) * Hn + n0 + tcol * 4) = o;
                }
            }
            __syncthreads();    // merge region dead before next job staging
        }
    }

    __threadfence();
    grid.sync();
    __threadfence();

    // ---- Phase 2: scores --------------------------------------------------
    {
        float* s_k  = smem;                        // [16][260]
        float* s_q  = smem + 16 * 260;             // [64][256]
        float* s_wv = smem + 16 * 260 + 64 * 256;  // [256]
        for (int job = blk; job < 512; job += 256) {
            const int kt = job & 63;
            const int qh = (job >> 6) & 1;
            const int b  = job >> 7;
            const int vlen = valid_lens[b];
            const int k0 = kt * 16;
            if (k0 >= vlen) continue;              // fully masked (block-uniform)
            const int q0 = qh * 64;

            const float4* k0p = (const float4*)(proj0 + ((size_t)512 + b * Kn + k0) * Hn);
            const float4* k1p = (const float4*)(proj1 + ((size_t)512 + b * Kn + k0) * Hn);
            #pragma unroll
            for (int i = 0; i < 2; ++i) {          // 16 rows x 64 f4
                int idx = t + i * 512;
                int row = idx >> 6, c4 = idx & 63;
                float4 a = k0p[idx], c = k1p[idx];
                a.x += c.x; a.y += c.y; a.z += c.z; a.w += c.w;
                *(float4*)&s_k[row * 260 + c4 * 4] = a;
            }
            const float4* q0p = (const float4*)(proj0 + ((size_t)b * Qn + q0) * Hn);
            const float4* q1p = (const float4*)(proj1 + ((size_t)b * Qn + q0) * Hn);
            #pragma unroll
            for (int i = 0; i < 8; ++i) {          // 64 rows x 64 f4, contiguous
                int idx = t + i * 512;
                float4 a = q0p[idx], c = q1p[idx];
                a.x += c.x; a.y += c.y; a.z += c.z; a.w += c.w;
                ((float4*)s_q)[idx] = a;
            }
            if (t < 64) ((float4*)s_wv)[t] = ((const float4*)wv)[t];
            __syncthreads();

            const int w = t >> 6, lane = t & 63;
            const int kloc = lane & 15, hq = lane >> 4;
            const float4* kr = (const float4*)&s_k[kloc * 260 + hq * 64];
            const float4* wr = (const float4*)&s_wv[hq * 64];
            const float*  qb = &s_q[(size_t)(w * 8) * 256 + hq * 64];
            float acc[8] = {0.f, 0.f, 0.f, 0.f, 0.f, 0.f, 0.f, 0.f};
            #pragma unroll 4
            for (int i = 0; i < 16; ++i) {
                float4 kv = kr[i];
                float4 wq = wr[i];
                #pragma unroll
                for (int qr = 0; qr < 8; ++qr) {
                    float4 qv = *(const float4*)&qb[qr * 256 + i * 4];
                    acc[qr] += wq.x * fast_tanh(qv.x + kv.x)
                             + wq.y * fast_tanh(qv.y + kv.y)
                             + wq.z * fast_tanh(qv.z + kv.z)
                             + wq.w * fast_tanh(qv.w + kv.w);
                }
            }
            const int k = k0 + kloc;
            #pragma unroll
            for (int qr = 0; qr < 8; ++qr) {
                float s = acc[qr];
                s += __shfl_xor(s, 16, 64);        // combine hq quarters
                s += __shfl_xor(s, 32, 64);
                float e = 0.f;
                if (lane < 16 && k < vlen) {
                    e = __expf(s);
                    escores[((size_t)b * Qn + q0 + w * 8 + qr) * Kn + k] = e;
                }
                e += __shfl_xor(e, 8, 64);
                e += __shfl_xor(e, 4, 64);
                e += __shfl_xor(e, 2, 64);
                e += __shfl_xor(e, 1, 64);
                if (lane == 0)
                    atomicAdd(&rowsum[b * Qn + q0 + w * 8 + qr], e);
            }
            __syncthreads();
        }
    }

    __threadfence();
    grid.sync();
    __threadfence();

    // ---- Phase 3: AV + normalize -----------------------------------------
    {
        float* s_e = smem;                  // [8][256]
        const int kc = blk & 3;
        const int qt = (blk >> 2) & 15;
        const int b  = blk >> 6;
        const int vlen = valid_lens[b];
        const int kb = kc * 256;
        if (kb < vlen) {
            const int q0 = qt * 8;
            const int row = t >> 6, c4 = t & 63;
            {
                const float* esrc = escores + ((size_t)b * Qn + q0 + row) * Kn + kb + c4 * 4;
                const int kbase = kb + c4 * 4;
                float4 ev;
                ev.x = (kbase + 0 < vlen) ? esrc[0] : 0.f;
                ev.y = (kbase + 1 < vlen) ? esrc[1] : 0.f;
                ev.z = (kbase + 2 < vlen) ? esrc[2] : 0.f;
                ev.w = (kbase + 3 < vlen) ? esrc[3] : 0.f;
                *(float4*)&s_e[row * 256 + c4 * 4] = ev;
            }
            __syncthreads();
            const int d = t;                // full D=512 per thread
            const float* vb = values + ((size_t)b * Kn + kb) * Dn + d;
            float acc[8] = {0.f, 0.f, 0.f, 0.f, 0.f, 0.f, 0.f, 0.f};
            #pragma unroll 2
            for (int k = 0; k < 256; k += 4) {
                float v0 = vb[(size_t)(k + 0) * Dn];
                float v1 = vb[(size_t)(k + 1) * Dn];
                float v2 = vb[(size_t)(k + 2) * Dn];
                float v3 = vb[(size_t)(k + 3) * Dn];
                #pragma unroll
                for (int j = 0; j < 8; ++j) {
                    float4 e4 = *(const float4*)&s_e[j * 256 + k];  // uniform bcast
                    acc[j] += e4.x * v0 + e4.y * v1 + e4.z * v2 + e4.w * v3;
                }
            }
            float* op = out + ((size_t)b * Qn + q0) * Dn + d;
            #pragma unroll
            for (int j = 0; j < 8; ++j) {
                float inv = __builtin_amdgcn_rcpf(rowsum[b * Qn + q0 + j]);
                atomicAdd(op + (size_t)j * Dn, acc[j] * inv);
            }
        }
    }
}

// ---------------------------------------------------------------------------
extern "C" void kernel_launch(void* const* d_in, const int* in_sizes, int n_in,
                              void* d_out, int out_size, void* d_ws, size_t ws_size,
                              hipStream_t stream) {
    const float* queries    = (const float*)d_in[0];
    const float* keys       = (const float*)d_in[1];
    const float* values     = (const float*)d_in[2];
    const int*   valid_lens = (const int*)  d_in[3];
    const float* Wq         = (const float*)d_in[4];
    const float* Wk         = (const float*)d_in[5];
    const float* wv         = (const float*)d_in[6];
    float* out = (float*)d_out;

    // ws layout: proj partials rows 0..511 = qproj, 512..4607 = kproj
    const size_t PROJ_F = (size_t)4608 * Hn;          // 1179648 floats each
    float* proj0   = (float*)d_ws;
    float* proj1   = proj0 + PROJ_F;
    float* escores = proj1 + PROJ_F;                  // [B*Q, K] 524288 f
    float* rowsum  = escores + (size_t)Bn * Qn * Kn;  // [B*Q]       512 f

    void* args[] = {(void*)&queries, (void*)&keys, (void*)&values,
                    (void*)&valid_lens, (void*)&Wq, (void*)&Wk, (void*)&wv,
                    (void*)&proj0, (void*)&proj1, (void*)&escores,
                    (void*)&rowsum, (void*)&out};
    hipLaunchCooperativeKernel(fused_kernel, dim3(256), dim3(512),
                               args, 0u, stream);
}

// Round 5
// 168.233 us; speedup vs baseline: 2.2695x; 2.2695x over previous
//
#include <hip/hip_runtime.h>

#define Bn 4
#define Qn 128
#define Kn 1024
#define Dn 512   // DQ = DK = DV = 512
#define Hn 256

// tanh(x) = 1 - 2/(1 + e^{2x}).  Inf-safe: e->inf => rcp(inf)=0 => 1.
__device__ __forceinline__ float fast_tanh(float x) {
    float e = __expf(2.0f * x);
    return 1.0f - 2.0f * __builtin_amdgcn_rcpf(1.0f + e);
}

// ---------------------------------------------------------------------------
// Kernel 1: projections GEMM [4608x512]@[512x256], 64x64 tile, BK=64.
// Structure = round-2 proven version: block-level split-K (kc in {0,1}, 256
// deep, disjoint proj0/proj1 partials summed by consumers) + 8-wave
// intra-block split (waves 0-3: kk 0..31, waves 4-7: kk 32..63) + LDS merge.
// NEW: blocks 0..127 zero `out` (for av's atomic accumulation) and block 0
// zeros rowsum at entry, BEFORE any masked early-return -> both memset
// dispatches are gone (stream order makes them visible to later kernels).
// ---------------------------------------------------------------------------
#define PBK 64

__global__ __launch_bounds__(512) void proj_kernel(
    const float* __restrict__ queries, const float* __restrict__ keys,
    const float* __restrict__ Wq, const float* __restrict__ Wk,
    const int* __restrict__ valid_lens,
    float* __restrict__ proj0, float* __restrict__ proj1,
    float* __restrict__ rowsum, float* __restrict__ out)
{
    const int blk = blockIdx.x;         // ((mt*4)+nt)*2 + kc
    const int t = threadIdx.x;

    // ---- fused zeroing (must precede any early return) -------------------
    if (blk < 128) {                    // 128 blk * 512 thr * 16 B = 1 MB
        float4 z = {0.f, 0.f, 0.f, 0.f};
        ((float4*)out)[blk * 512 + t] = z;
        if (blk == 0) rowsum[t] = 0.f;  // 512 floats
    }

    const int kc = blk & 1;
    const int nt = (blk >> 1) & 3;
    const int mt = blk >> 3;            // 0..71
    const float* Asrc; const float* W;
    int m0, drow;
    if (mt < 8) {                       // query rows (512 = B*Q)
        m0 = mt * 64;
        drow = m0;
        Asrc = queries; W = Wq;
    } else {                            // key rows (4096 = B*K)
        int r0 = (mt - 8) * 64;
        int b = r0 >> 10;
        if ((r0 & 1023) >= valid_lens[b]) return;   // tile fully masked
        m0 = r0;
        drow = 512 + r0;
        Asrc = keys; W = Wk;
    }
    const int n0 = nt * 64;
    const int k0 = kc * 256;            // this block's K-chunk
    float* Dst = (kc ? proj1 : proj0) + (size_t)drow * Hn;

    __shared__ float s_a[PBK][68];      // A^T tile [k][m], pad 68 (17408 B)
    __shared__ float s_b[PBK][64];      // B tile   [k][n]   (16384 B)

    const int tt   = t & 255;           // position within k-half
    const int kh   = t >> 8;            // 0 -> kk 0..31, 1 -> kk 32..63
    const int trow = tt >> 4;           // 0..15 (x4 m)
    const int tcol = tt & 15;           // 0..15 (x4 n)
    const int kklo = kh << 5;

    const int lrow = t >> 4;            // 0..31 (staging row)
    const int lc4  = t & 15;

    float acc[4][4] = {{0.f}};
    float4 ra[2], rb[2];

    #pragma unroll
    for (int i = 0; i < 2; ++i) {       // preload kt=0
        ra[i] = *(const float4*)(Asrc + (size_t)(m0 + lrow + i * 32) * Dn + k0 + lc4 * 4);
        rb[i] = *(const float4*)(W + (size_t)(k0 + lrow + i * 32) * Hn + n0 + lc4 * 4);
    }

    for (int kt = 0; kt < 4; ++kt) {
        __syncthreads();                // prev compute done before overwrite
        #pragma unroll
        for (int i = 0; i < 2; ++i) {   // regs -> LDS (waits vmcnt here)
            int row = lrow + i * 32;
            s_a[lc4 * 4 + 0][row] = ra[i].x;
            s_a[lc4 * 4 + 1][row] = ra[i].y;
            s_a[lc4 * 4 + 2][row] = ra[i].z;
            s_a[lc4 * 4 + 3][row] = ra[i].w;
            *(float4*)&s_b[row][lc4 * 4] = rb[i];
        }
        __syncthreads();
        if (kt < 3) {                   // prefetch kt+1 (overlaps compute)
            const int d0n = k0 + (kt + 1) * PBK;
            #pragma unroll
            for (int i = 0; i < 2; ++i) {
                ra[i] = *(const float4*)(Asrc + (size_t)(m0 + lrow + i * 32) * Dn + d0n + lc4 * 4);
                rb[i] = *(const float4*)(W + (size_t)(d0n + lrow + i * 32) * Hn + n0 + lc4 * 4);
            }
        }
        #pragma unroll
        for (int kk = 0; kk < 32; ++kk) {
            float4 a4 = *(const float4*)&s_a[kklo + kk][trow * 4];
            float4 b4 = *(const float4*)&s_b[kklo + kk][tcol * 4];
            float a[4] = {a4.x, a4.y, a4.z, a4.w};
            float b[4] = {b4.x, b4.y, b4.z, b4.w};
            #pragma unroll
            for (int i = 0; i < 4; ++i)
                #pragma unroll
                for (int j = 0; j < 4; ++j)
                    acc[i][j] += a[i] * b[j];
        }
    }

    // merge the two k-halves through LDS (s_a region: 256*17 floats,
    // stride 17 keeps the scalar accesses conflict-free)
    __syncthreads();
    float* red = &s_a[0][0];
    if (kh) {
        #pragma unroll
        for (int i = 0; i < 4; ++i)
            #pragma unroll
            for (int j = 0; j < 4; ++j)
                red[tt * 17 + i * 4 + j] = acc[i][j];
    }
    __syncthreads();
    if (!kh) {
        #pragma unroll
        for (int i = 0; i < 4; ++i) {
            float4 o;
            o.x = acc[i][0] + red[tt * 17 + i * 4 + 0];
            o.y = acc[i][1] + red[tt * 17 + i * 4 + 1];
            o.z = acc[i][2] + red[tt * 17 + i * 4 + 2];
            o.w = acc[i][3] + red[tt * 17 + i * 4 + 3];
            *(float4*)(Dst + (size_t)(trow * 4 + i) * Hn + n0 + tcol * 4) = o;
        }
    }
}

// ---------------------------------------------------------------------------
// Kernel 2: scores. v4: q-panel reuse (ported from the coop P2, standalone).
// Grid 1024 = b(4) x qp(4: 32 q-rows) x kt(64: 16 k). 256 threads, 4 waves;
// wave = 16 kloc x 4 hq lanes, handles 8 q-rows: each K/wv fragment register
// load amortizes over 8 q-rows. vs round-2: kproj global re-reads drop 32x ->
// 4x (total staging traffic ~400 MB -> ~66 MB), LDS ~50 KB -> 3 blocks/CU
// (12 waves). e = exp(score) (max-free: |s| <= sum|wv|), atomic rowsum.
// ---------------------------------------------------------------------------
__global__ __launch_bounds__(256) void score_kernel(
    const float* __restrict__ proj0, const float* __restrict__ proj1,
    const float* __restrict__ wv, const int* __restrict__ valid_lens,
    float* __restrict__ escores, float* __restrict__ rowsum)
{
    const int blk = blockIdx.x;             // ((b*4 + qp)*64 + kt)
    const int kt = blk & 63;
    const int qp = (blk >> 6) & 3;
    const int b  = blk >> 8;
    const int vlen = valid_lens[b];
    const int k0 = kt * 16;
    if (k0 >= vlen) return;                 // fully-masked tile
    const int q0 = qp * 32;
    const int t = threadIdx.x;

    __shared__ float s_k[16 * 260];         // 16640 B (pad 260)
    __shared__ float s_q[32 * 256];         // 32768 B
    __shared__ float s_wv[Hn];              // 1024 B

    {
        const float4* k0p = (const float4*)(proj0 + ((size_t)(512 + b * Kn + k0)) * Hn);
        const float4* k1p = (const float4*)(proj1 + ((size_t)(512 + b * Kn + k0)) * Hn);
        #pragma unroll
        for (int i = 0; i < 4; ++i) {       // 16 rows x 64 float4
            int idx = t + i * 256;
            int row = idx >> 6, c4 = idx & 63;
            float4 a = k0p[idx], c = k1p[idx];
            a.x += c.x; a.y += c.y; a.z += c.z; a.w += c.w;
            *(float4*)&s_k[row * 260 + c4 * 4] = a;
        }
        const float4* q0p = (const float4*)(proj0 + ((size_t)(b * Qn + q0)) * Hn);
        const float4* q1p = (const float4*)(proj1 + ((size_t)(b * Qn + q0)) * Hn);
        #pragma unroll
        for (int i = 0; i < 8; ++i) {       // 32 rows x 64 float4, contiguous
            int idx = t + i * 256;
            float4 a = q0p[idx], c = q1p[idx];
            a.x += c.x; a.y += c.y; a.z += c.z; a.w += c.w;
            ((float4*)s_q)[idx] = a;
        }
        if (t < 64) ((float4*)s_wv)[t] = ((const float4*)wv)[t];
    }
    __syncthreads();

    const int w = t >> 6, lane = t & 63;
    const int kloc = lane & 15, hq = lane >> 4;   // h-quarter: 64 h each
    const float4* kr = (const float4*)&s_k[kloc * 260 + hq * 64];
    const float4* wr = (const float4*)&s_wv[hq * 64];
    const float*  qb = &s_q[(size_t)(w * 8) * 256 + hq * 64];

    float acc[8] = {0.f, 0.f, 0.f, 0.f, 0.f, 0.f, 0.f, 0.f};
    #pragma unroll 4
    for (int i = 0; i < 16; ++i) {          // 16 float4 = 64 h per lane
        float4 kv = kr[i];
        float4 wq = wr[i];
        #pragma unroll
        for (int qr = 0; qr < 8; ++qr) {
            float4 qv = *(const float4*)&qb[qr * 256 + i * 4];
            acc[qr] += wq.x * fast_tanh(qv.x + kv.x)
                     + wq.y * fast_tanh(qv.y + kv.y)
                     + wq.z * fast_tanh(qv.z + kv.z)
                     + wq.w * fast_tanh(qv.w + kv.w);
        }
    }
    const int k = k0 + kloc;
    #pragma unroll
    for (int qr = 0; qr < 8; ++qr) {
        float s = acc[qr];
        s += __shfl_xor(s, 16, 64);         // combine hq quarters
        s += __shfl_xor(s, 32, 64);
        float e = 0.f;
        if (lane < 16 && k < vlen) {
            e = __expf(s);
            escores[((size_t)(b * Qn + q0 + w * 8 + qr)) * Kn + k] = e;
        }
        e += __shfl_xor(e, 8, 64);
        e += __shfl_xor(e, 4, 64);
        e += __shfl_xor(e, 2, 64);
        e += __shfl_xor(e, 1, 64);
        if (lane == 0)
            atomicAdd(&rowsum[b * Qn + q0 + w * 8 + qr], e);
    }
}

// ---------------------------------------------------------------------------
// Kernel 3: AV + fused normalize. Grid 256 = b(4) x qt(8: 16 q-rows) x
// kc(8: 128 k). Thread covers 2 d (float2 V loads): 16q x 2d per thread ->
// e-broadcast LDS instrs amortize 1:8 vs FMA (was 1:4), V global re-reads
// drop 16x -> 8x. escores staged with per-component k<vlen guard (masked ->
// 0, no escores memset); fully-masked chunks skip. acc * rcp(rowsum)
// atomically accumulated into out (zeroed by proj).
// ---------------------------------------------------------------------------
__global__ __launch_bounds__(256) void av_kernel(
    const float* __restrict__ escores, const float* __restrict__ values,
    const float* __restrict__ rowsum, const int* __restrict__ valid_lens,
    float* __restrict__ out)
{
    const int blk = blockIdx.x;         // ((b*8 + qt)*8 + kc)
    const int kc = blk & 7;
    const int qt = (blk >> 3) & 7;
    const int b  = blk >> 6;
    const int vlen = valid_lens[b];
    const int kb = kc * 128;
    if (kb >= vlen) return;             // fully-masked chunk
    const int q0 = qt * 16;
    const int t = threadIdx.x;

    __shared__ float s_e[16 * 128];     // 8 KB
    #pragma unroll
    for (int i = 0; i < 2; ++i) {       // 16 rows x 32 float4 = 512 f4
        int idx = t + i * 256;
        int row = idx >> 5, c4 = idx & 31;
        const float* esrc = escores + ((size_t)(b * Qn + q0 + row)) * Kn + kb + c4 * 4;
        int kbase = kb + c4 * 4;
        float4 ev;
        ev.x = (kbase + 0 < vlen) ? esrc[0] : 0.f;
        ev.y = (kbase + 1 < vlen) ? esrc[1] : 0.f;
        ev.z = (kbase + 2 < vlen) ? esrc[2] : 0.f;
        ev.w = (kbase + 3 < vlen) ? esrc[3] : 0.f;
        *(float4*)&s_e[row * 128 + c4 * 4] = ev;
    }
    __syncthreads();

    const int d0 = t * 2;               // 256 threads cover D=512
    const float* vb = values + ((size_t)(b * Kn + kb)) * Dn + d0;
    float accx[16], accy[16];
    #pragma unroll
    for (int j = 0; j < 16; ++j) { accx[j] = 0.f; accy[j] = 0.f; }

    #pragma unroll 2
    for (int k = 0; k < 128; k += 4) {
        float2 v0 = *(const float2*)&vb[(size_t)(k + 0) * Dn];
        float2 v1 = *(const float2*)&vb[(size_t)(k + 1) * Dn];
        float2 v2 = *(const float2*)&vb[(size_t)(k + 2) * Dn];
        float2 v3 = *(const float2*)&vb[(size_t)(k + 3) * Dn];
        #pragma unroll
        for (int j = 0; j < 16; ++j) {
            float4 e4 = *(const float4*)&s_e[j * 128 + k];  // uniform bcast
            accx[j] += e4.x * v0.x + e4.y * v1.x + e4.z * v2.x + e4.w * v3.x;
            accy[j] += e4.x * v0.y + e4.y * v1.y + e4.z * v2.y + e4.w * v3.y;
        }
    }
    float* op = out + ((size_t)(b * Qn + q0)) * Dn + d0;
    #pragma unroll
    for (int j = 0; j < 16; ++j) {
        float inv = __builtin_amdgcn_rcpf(rowsum[b * Qn + q0 + j]);
        atomicAdd(op + (size_t)j * Dn + 0, accx[j] * inv);
        atomicAdd(op + (size_t)j * Dn + 1, accy[j] * inv);
    }
}

// ---------------------------------------------------------------------------
extern "C" void kernel_launch(void* const* d_in, const int* in_sizes, int n_in,
                              void* d_out, int out_size, void* d_ws, size_t ws_size,
                              hipStream_t stream) {
    const float* queries    = (const float*)d_in[0];
    const float* keys       = (const float*)d_in[1];
    const float* values     = (const float*)d_in[2];
    const int*   valid_lens = (const int*)  d_in[3];
    const float* Wq         = (const float*)d_in[4];
    const float* Wk         = (const float*)d_in[5];
    const float* wv         = (const float*)d_in[6];
    float* out = (float*)d_out;

    // ws layout: proj partials rows 0..511 = qproj, 512..4607 = kproj
    const size_t PROJ_F = (size_t)4608 * Hn;          // 1179648 floats each
    float* proj0   = (float*)d_ws;
    float* proj1   = proj0 + PROJ_F;
    float* escores = proj1 + PROJ_F;                  // [B*Q, K] 524288 f
    float* rowsum  = escores + (size_t)Bn * Qn * Kn;  // [B*Q]       512 f

    // 3 dispatches, zero memsets (zeroing fused into proj_kernel)
    proj_kernel<<<576, 512, 0, stream>>>(queries, keys, Wq, Wk, valid_lens,
                                         proj0, proj1, rowsum, out);
    score_kernel<<<1024, 256, 0, stream>>>(proj0, proj1, wv, valid_lens,
                                           escores, rowsum);
    av_kernel<<<256, 256, 0, stream>>>(escores, values, rowsum, valid_lens,
                                       out);
}

// Round 6
// 167.970 us; speedup vs baseline: 2.2731x; 1.0016x over previous
//
#include <hip/hip_runtime.h>

#define Bn 4
#define Qn 128
#define Kn 1024
#define Dn 512   // DQ = DK = DV = 512
#define Hn 256

// tanh(x) = 1 - 2/(1 + e^{2x}).  Inf-safe: e->inf => rcp(inf)=0 => 1.
__device__ __forceinline__ float fast_tanh(float x) {
    float e = __expf(2.0f * x);
    return 1.0f - 2.0f * __builtin_amdgcn_rcpf(1.0f + e);
}

// ---------------------------------------------------------------------------
// Kernel 1: projections GEMM [4608x512]@[512x256], 64x64 tile, BK=64.
// Block-level split-K (kc in {0,1}, 256 deep, disjoint proj0/proj1 partials
// summed by consumers) + 8-wave intra-block split (waves 0-3: kk 0..31,
// waves 4-7: kk 32..63) + LDS merge. Blocks 0..127 zero `out`, block 0 zeros
// rowsum at entry (before any masked early-return) -> no memset dispatches.
// ---------------------------------------------------------------------------
#define PBK 64

__global__ __launch_bounds__(512) void proj_kernel(
    const float* __restrict__ queries, const float* __restrict__ keys,
    const float* __restrict__ Wq, const float* __restrict__ Wk,
    const int* __restrict__ valid_lens,
    float* __restrict__ proj0, float* __restrict__ proj1,
    float* __restrict__ rowsum, float* __restrict__ out)
{
    const int blk = blockIdx.x;         // ((mt*4)+nt)*2 + kc
    const int t = threadIdx.x;

    // ---- fused zeroing (must precede any early return) -------------------
    if (blk < 128) {                    // 128 blk * 512 thr * 16 B = 1 MB
        float4 z = {0.f, 0.f, 0.f, 0.f};
        ((float4*)out)[blk * 512 + t] = z;
        if (blk == 0) rowsum[t] = 0.f;  // 512 floats
    }

    const int kc = blk & 1;
    const int nt = (blk >> 1) & 3;
    const int mt = blk >> 3;            // 0..71
    const float* Asrc; const float* W;
    int m0, drow;
    if (mt < 8) {                       // query rows (512 = B*Q)
        m0 = mt * 64;
        drow = m0;
        Asrc = queries; W = Wq;
    } else {                            // key rows (4096 = B*K)
        int r0 = (mt - 8) * 64;
        int b = r0 >> 10;
        if ((r0 & 1023) >= valid_lens[b]) return;   // tile fully masked
        m0 = r0;
        drow = 512 + r0;
        Asrc = keys; W = Wk;
    }
    const int n0 = nt * 64;
    const int k0 = kc * 256;            // this block's K-chunk
    float* Dst = (kc ? proj1 : proj0) + (size_t)drow * Hn;

    __shared__ float s_a[PBK][68];      // A^T tile [k][m], pad 68 (17408 B)
    __shared__ float s_b[PBK][64];      // B tile   [k][n]   (16384 B)

    const int tt   = t & 255;           // position within k-half
    const int kh   = t >> 8;            // 0 -> kk 0..31, 1 -> kk 32..63
    const int trow = tt >> 4;           // 0..15 (x4 m)
    const int tcol = tt & 15;           // 0..15 (x4 n)
    const int kklo = kh << 5;

    const int lrow = t >> 4;            // 0..31 (staging row)
    const int lc4  = t & 15;

    float acc[4][4] = {{0.f}};
    float4 ra[2], rb[2];

    #pragma unroll
    for (int i = 0; i < 2; ++i) {       // preload kt=0
        ra[i] = *(const float4*)(Asrc + (size_t)(m0 + lrow + i * 32) * Dn + k0 + lc4 * 4);
        rb[i] = *(const float4*)(W + (size_t)(k0 + lrow + i * 32) * Hn + n0 + lc4 * 4);
    }

    for (int kt = 0; kt < 4; ++kt) {
        __syncthreads();                // prev compute done before overwrite
        #pragma unroll
        for (int i = 0; i < 2; ++i) {   // regs -> LDS (waits vmcnt here)
            int row = lrow + i * 32;
            s_a[lc4 * 4 + 0][row] = ra[i].x;
            s_a[lc4 * 4 + 1][row] = ra[i].y;
            s_a[lc4 * 4 + 2][row] = ra[i].z;
            s_a[lc4 * 4 + 3][row] = ra[i].w;
            *(float4*)&s_b[row][lc4 * 4] = rb[i];
        }
        __syncthreads();
        if (kt < 3) {                   // prefetch kt+1 (overlaps compute)
            const int d0n = k0 + (kt + 1) * PBK;
            #pragma unroll
            for (int i = 0; i < 2; ++i) {
                ra[i] = *(const float4*)(Asrc + (size_t)(m0 + lrow + i * 32) * Dn + d0n + lc4 * 4);
                rb[i] = *(const float4*)(W + (size_t)(d0n + lrow + i * 32) * Hn + n0 + lc4 * 4);
            }
        }
        #pragma unroll
        for (int kk = 0; kk < 32; ++kk) {
            float4 a4 = *(const float4*)&s_a[kklo + kk][trow * 4];
            float4 b4 = *(const float4*)&s_b[kklo + kk][tcol * 4];
            float a[4] = {a4.x, a4.y, a4.z, a4.w};
            float b[4] = {b4.x, b4.y, b4.z, b4.w};
            #pragma unroll
            for (int i = 0; i < 4; ++i)
                #pragma unroll
                for (int j = 0; j < 4; ++j)
                    acc[i][j] += a[i] * b[j];
        }
    }

    // merge the two k-halves through LDS (s_a region: 256*17 floats,
    // stride 17 keeps the scalar accesses conflict-free)
    __syncthreads();
    float* red = &s_a[0][0];
    if (kh) {
        #pragma unroll
        for (int i = 0; i < 4; ++i)
            #pragma unroll
            for (int j = 0; j < 4; ++j)
                red[tt * 17 + i * 4 + j] = acc[i][j];
    }
    __syncthreads();
    if (!kh) {
        #pragma unroll
        for (int i = 0; i < 4; ++i) {
            float4 o;
            o.x = acc[i][0] + red[tt * 17 + i * 4 + 0];
            o.y = acc[i][1] + red[tt * 17 + i * 4 + 1];
            o.z = acc[i][2] + red[tt * 17 + i * 4 + 2];
            o.w = acc[i][3] + red[tt * 17 + i * 4 + 3];
            *(float4*)(Dst + (size_t)(trow * 4 + i) * Hn + n0 + tcol * 4) = o;
        }
    }
}

// ---------------------------------------------------------------------------
// Kernel 2: scores. v5: bank-conflict-free LDS layout.
// R5 measured 49 us at 0.23% HBM -> LDS-bound. Root cause: hq quarters were
// offset by 64 floats = 256 B = 0 banks -> every qv broadcast read (128
// ds_read_b128 per wave-job, the dominant term) was a 4-way bank conflict,
// and kr reads an 8-way.
// Fix: layout [row][hq][68] (68 mod 32 = 4 banks): the 4 hq broadcast
// addresses now hit banks {0-3,4-7,8-11,12-15} -> conflict-free.
// Grid 1024 = b(4) x qp(4: 32 q) x kt(64: 16 k); wave = 16 kloc x 4 hq,
// 8 q-rows per wave (K/wv fragments amortize over 8 q). LDS 53.3 KB ->
// 3 blocks/CU. e = exp(score) (max-free: |s| <= sum|wv|), atomic rowsum.
// ---------------------------------------------------------------------------
#define HQS 68          // hq quarter stride (floats): 4-bank offset
#define QRS 272         // row stride = 4 * HQS

__global__ __launch_bounds__(256) void score_kernel(
    const float* __restrict__ proj0, const float* __restrict__ proj1,
    const float* __restrict__ wv, const int* __restrict__ valid_lens,
    float* __restrict__ escores, float* __restrict__ rowsum)
{
    const int blk = blockIdx.x;             // ((b*4 + qp)*64 + kt)
    const int kt = blk & 63;
    const int qp = (blk >> 6) & 3;
    const int b  = blk >> 8;
    const int vlen = valid_lens[b];
    const int k0 = kt * 16;
    if (k0 >= vlen) return;                 // fully-masked tile
    const int q0 = qp * 32;
    const int t = threadIdx.x;

    __shared__ float s_k[16 * QRS];         // 17408 B
    __shared__ float s_q[32 * QRS];         // 34816 B
    __shared__ float s_wv[QRS];             //  1088 B

    {
        const float4* k0p = (const float4*)(proj0 + ((size_t)(512 + b * Kn + k0)) * Hn);
        const float4* k1p = (const float4*)(proj1 + ((size_t)(512 + b * Kn + k0)) * Hn);
        #pragma unroll
        for (int i = 0; i < 4; ++i) {       // 16 rows x 64 float4
            int idx = t + i * 256;
            int row = idx >> 6, c4 = idx & 63;
            float4 a = k0p[idx], c = k1p[idx];
            a.x += c.x; a.y += c.y; a.z += c.z; a.w += c.w;
            *(float4*)&s_k[row * QRS + (c4 >> 4) * HQS + (c4 & 15) * 4] = a;
        }
        const float4* q0p = (const float4*)(proj0 + ((size_t)(b * Qn + q0)) * Hn);
        const float4* q1p = (const float4*)(proj1 + ((size_t)(b * Qn + q0)) * Hn);
        #pragma unroll
        for (int i = 0; i < 8; ++i) {       // 32 rows x 64 float4
            int idx = t + i * 256;
            int row = idx >> 6, c4 = idx & 63;
            float4 a = q0p[idx], c = q1p[idx];
            a.x += c.x; a.y += c.y; a.z += c.z; a.w += c.w;
            *(float4*)&s_q[row * QRS + (c4 >> 4) * HQS + (c4 & 15) * 4] = a;
        }
        if (t < 64)
            *(float4*)&s_wv[(t >> 4) * HQS + (t & 15) * 4] =
                ((const float4*)wv)[t];
    }
    __syncthreads();

    const int w = t >> 6, lane = t & 63;
    const int kloc = lane & 15, hq = lane >> 4;   // h-quarter: 64 h each
    const float4* kr = (const float4*)&s_k[kloc * QRS + hq * HQS];
    const float4* wr = (const float4*)&s_wv[hq * HQS];
    const float*  qb = &s_q[(size_t)(w * 8) * QRS + hq * HQS];

    float acc[8] = {0.f, 0.f, 0.f, 0.f, 0.f, 0.f, 0.f, 0.f};
    #pragma unroll 4
    for (int i = 0; i < 16; ++i) {          // 16 float4 = 64 h per lane
        float4 kv = kr[i];
        float4 wq = wr[i];
        #pragma unroll
        for (int qr = 0; qr < 8; ++qr) {
            float4 qv = *(const float4*)&qb[qr * QRS + i * 4];
            acc[qr] += wq.x * fast_tanh(qv.x + kv.x)
                     + wq.y * fast_tanh(qv.y + kv.y)
                     + wq.z * fast_tanh(qv.z + kv.z)
                     + wq.w * fast_tanh(qv.w + kv.w);
        }
    }
    const int k = k0 + kloc;
    #pragma unroll
    for (int qr = 0; qr < 8; ++qr) {
        float s = acc[qr];
        s += __shfl_xor(s, 16, 64);         // combine hq quarters
        s += __shfl_xor(s, 32, 64);
        float e = 0.f;
        if (lane < 16 && k < vlen) {
            e = __expf(s);
            escores[((size_t)(b * Qn + q0 + w * 8 + qr)) * Kn + k] = e;
        }
        e += __shfl_xor(e, 8, 64);
        e += __shfl_xor(e, 4, 64);
        e += __shfl_xor(e, 2, 64);
        e += __shfl_xor(e, 1, 64);
        if (lane == 0)
            atomicAdd(&rowsum[b * Qn + q0 + w * 8 + qr], e);
    }
}

// ---------------------------------------------------------------------------
// Kernel 3: AV + fused normalize. Grid 256 = b(4) x qt(8: 16 q-rows) x
// kc(8: 128 k). Thread covers 2 d (float2 V loads): 16q x 2d per thread ->
// e-broadcast LDS instrs amortize 1:8 vs FMA, V global re-reads 8x. escores
// staged with per-component k<vlen guard (masked -> 0, no escores memset);
// fully-masked chunks skip. acc * rcp(rowsum) atomically into zeroed out.
// ---------------------------------------------------------------------------
__global__ __launch_bounds__(256) void av_kernel(
    const float* __restrict__ escores, const float* __restrict__ values,
    const float* __restrict__ rowsum, const int* __restrict__ valid_lens,
    float* __restrict__ out)
{
    const int blk = blockIdx.x;         // ((b*8 + qt)*8 + kc)
    const int kc = blk & 7;
    const int qt = (blk >> 3) & 7;
    const int b  = blk >> 6;
    const int vlen = valid_lens[b];
    const int kb = kc * 128;
    if (kb >= vlen) return;             // fully-masked chunk
    const int q0 = qt * 16;
    const int t = threadIdx.x;

    __shared__ float s_e[16 * 128];     // 8 KB
    #pragma unroll
    for (int i = 0; i < 2; ++i) {       // 16 rows x 32 float4 = 512 f4
        int idx = t + i * 256;
        int row = idx >> 5, c4 = idx & 31;
        const float* esrc = escores + ((size_t)(b * Qn + q0 + row)) * Kn + kb + c4 * 4;
        int kbase = kb + c4 * 4;
        float4 ev;
        ev.x = (kbase + 0 < vlen) ? esrc[0] : 0.f;
        ev.y = (kbase + 1 < vlen) ? esrc[1] : 0.f;
        ev.z = (kbase + 2 < vlen) ? esrc[2] : 0.f;
        ev.w = (kbase + 3 < vlen) ? esrc[3] : 0.f;
        *(float4*)&s_e[row * 128 + c4 * 4] = ev;
    }
    __syncthreads();

    const int d0 = t * 2;               // 256 threads cover D=512
    const float* vb = values + ((size_t)(b * Kn + kb)) * Dn + d0;
    float accx[16], accy[16];
    #pragma unroll
    for (int j = 0; j < 16; ++j) { accx[j] = 0.f; accy[j] = 0.f; }

    #pragma unroll 2
    for (int k = 0; k < 128; k += 4) {
        float2 v0 = *(const float2*)&vb[(size_t)(k + 0) * Dn];
        float2 v1 = *(const float2*)&vb[(size_t)(k + 1) * Dn];
        float2 v2 = *(const float2*)&vb[(size_t)(k + 2) * Dn];
        float2 v3 = *(const float2*)&vb[(size_t)(k + 3) * Dn];
        #pragma unroll
        for (int j = 0; j < 16; ++j) {
            float4 e4 = *(const float4*)&s_e[j * 128 + k];  // uniform bcast
            accx[j] += e4.x * v0.x + e4.y * v1.x + e4.z * v2.x + e4.w * v3.x;
            accy[j] += e4.x * v0.y + e4.y * v1.y + e4.z * v2.y + e4.w * v3.y;
        }
    }
    float* op = out + ((size_t)(b * Qn + q0)) * Dn + d0;
    #pragma unroll
    for (int j = 0; j < 16; ++j) {
        float inv = __builtin_amdgcn_rcpf(rowsum[b * Qn + q0 + j]);
        atomicAdd(op + (size_t)j * Dn + 0, accx[j] * inv);
        atomicAdd(op + (size_t)j * Dn + 1, accy[j] * inv);
    }
}

// ---------------------------------------------------------------------------
extern "C" void kernel_launch(void* const* d_in, const int* in_sizes, int n_in,
                              void* d_out, int out_size, void* d_ws, size_t ws_size,
                              hipStream_t stream) {
    const float* queries    = (const float*)d_in[0];
    const float* keys       = (const float*)d_in[1];
    const float* values     = (const float*)d_in[2];
    const int*   valid_lens = (const int*)  d_in[3];
    const float* Wq         = (const float*)d_in[4];
    const float* Wk         = (const float*)d_in[5];
    const float* wv         = (const float*)d_in[6];
    float* out = (float*)d_out;

    // ws layout: proj partials rows 0..511 = qproj, 512..4607 = kproj
    const size_t PROJ_F = (size_t)4608 * Hn;          // 1179648 floats each
    float* proj0   = (float*)d_ws;
    float* proj1   = proj0 + PROJ_F;
    float* escores = proj1 + PROJ_F;                  // [B*Q, K] 524288 f
    float* rowsum  = escores + (size_t)Bn * Qn * Kn;  // [B*Q]       512 f

    // 3 dispatches, zero memsets (zeroing fused into proj_kernel)
    proj_kernel<<<576, 512, 0, stream>>>(queries, keys, Wq, Wk, valid_lens,
                                         proj0, proj1, rowsum, out);
    score_kernel<<<1024, 256, 0, stream>>>(proj0, proj1, wv, valid_lens,
                                           escores, rowsum);
    av_kernel<<<256, 256, 0, stream>>>(escores, values, rowsum, valid_lens,
                                       out);
}

// Round 9
// 157.902 us; speedup vs baseline: 2.4180x; 1.0638x over previous
//
#include <hip/hip_runtime.h>

#define Bn 4
#define Qn 128
#define Kn 1024
#define Dn 512   // DQ = DK = DV = 512
#define Hn 256

// tanh(x) = 1 - 2/(1 + e^{2x}).  Inf-safe: e->inf => rcp(inf)=0 => 1.
__device__ __forceinline__ float fast_tanh(float x) {
    float e = __expf(2.0f * x);
    return 1.0f - 2.0f * __builtin_amdgcn_rcpf(1.0f + e);
}

// ---------------------------------------------------------------------------
// Kernel 1: projections GEMM [4608x512]@[512x256], 64x64 tile, BK=64.
// Block-level split-K (kc in {0,1}, 256 deep, disjoint proj0/proj1 partials
// summed by consumers) + 8-wave intra-block split (waves 0-3: kk 0..31,
// waves 4-7: kk 32..63) + LDS merge. Blocks 0..127 zero `out`, block 0 zeros
// rowsum at entry (before any masked early-return) -> no memset dispatches.
// ---------------------------------------------------------------------------
#define PBK 64

__global__ __launch_bounds__(512) void proj_kernel(
    const float* __restrict__ queries, const float* __restrict__ keys,
    const float* __restrict__ Wq, const float* __restrict__ Wk,
    const int* __restrict__ valid_lens,
    float* __restrict__ proj0, float* __restrict__ proj1,
    float* __restrict__ rowsum, float* __restrict__ out)
{
    const int blk = blockIdx.x;         // ((mt*4)+nt)*2 + kc
    const int t = threadIdx.x;

    // ---- fused zeroing (must precede any early return) -------------------
    if (blk < 128) {                    // 128 blk * 512 thr * 16 B = 1 MB
        float4 z = {0.f, 0.f, 0.f, 0.f};
        ((float4*)out)[blk * 512 + t] = z;
        if (blk == 0) rowsum[t] = 0.f;  // 512 floats
    }

    const int kc = blk & 1;
    const int nt = (blk >> 1) & 3;
    const int mt = blk >> 3;            // 0..71
    const float* Asrc; const float* W;
    int m0, drow;
    if (mt < 8) {                       // query rows (512 = B*Q)
        m0 = mt * 64;
        drow = m0;
        Asrc = queries; W = Wq;
    } else {                            // key rows (4096 = B*K)
        int r0 = (mt - 8) * 64;
        int b = r0 >> 10;
        if ((r0 & 1023) >= valid_lens[b]) return;   // tile fully masked
        m0 = r0;
        drow = 512 + r0;
        Asrc = keys; W = Wk;
    }
    const int n0 = nt * 64;
    const int k0 = kc * 256;            // this block's K-chunk
    float* Dst = (kc ? proj1 : proj0) + (size_t)drow * Hn;

    __shared__ float s_a[PBK][68];      // A^T tile [k][m], pad 68 (17408 B)
    __shared__ float s_b[PBK][64];      // B tile   [k][n]   (16384 B)

    const int tt   = t & 255;           // position within k-half
    const int kh   = t >> 8;            // 0 -> kk 0..31, 1 -> kk 32..63
    const int trow = tt >> 4;           // 0..15 (x4 m)
    const int tcol = tt & 15;           // 0..15 (x4 n)
    const int kklo = kh << 5;

    const int lrow = t >> 4;            // 0..31 (staging row)
    const int lc4  = t & 15;

    float acc[4][4] = {{0.f}};
    float4 ra[2], rb[2];

    #pragma unroll
    for (int i = 0; i < 2; ++i) {       // preload kt=0
        ra[i] = *(const float4*)(Asrc + (size_t)(m0 + lrow + i * 32) * Dn + k0 + lc4 * 4);
        rb[i] = *(const float4*)(W + (size_t)(k0 + lrow + i * 32) * Hn + n0 + lc4 * 4);
    }

    for (int kt = 0; kt < 4; ++kt) {
        __syncthreads();                // prev compute done before overwrite
        #pragma unroll
        for (int i = 0; i < 2; ++i) {   // regs -> LDS (waits vmcnt here)
            int row = lrow + i * 32;
            s_a[lc4 * 4 + 0][row] = ra[i].x;
            s_a[lc4 * 4 + 1][row] = ra[i].y;
            s_a[lc4 * 4 + 2][row] = ra[i].z;
            s_a[lc4 * 4 + 3][row] = ra[i].w;
            *(float4*)&s_b[row][lc4 * 4] = rb[i];
        }
        __syncthreads();
        if (kt < 3) {                   // prefetch kt+1 (overlaps compute)
            const int d0n = k0 + (kt + 1) * PBK;
            #pragma unroll
            for (int i = 0; i < 2; ++i) {
                ra[i] = *(const float4*)(Asrc + (size_t)(m0 + lrow + i * 32) * Dn + d0n + lc4 * 4);
                rb[i] = *(const float4*)(W + (size_t)(d0n + lrow + i * 32) * Hn + n0 + lc4 * 4);
            }
        }
        #pragma unroll
        for (int kk = 0; kk < 32; ++kk) {
            float4 a4 = *(const float4*)&s_a[kklo + kk][trow * 4];
            float4 b4 = *(const float4*)&s_b[kklo + kk][tcol * 4];
            float a[4] = {a4.x, a4.y, a4.z, a4.w};
            float b[4] = {b4.x, b4.y, b4.z, b4.w};
            #pragma unroll
            for (int i = 0; i < 4; ++i)
                #pragma unroll
                for (int j = 0; j < 4; ++j)
                    acc[i][j] += a[i] * b[j];
        }
    }

    // merge the two k-halves through LDS (s_a region: 256*17 floats,
    // stride 17 keeps the scalar accesses conflict-free)
    __syncthreads();
    float* red = &s_a[0][0];
    if (kh) {
        #pragma unroll
        for (int i = 0; i < 4; ++i)
            #pragma unroll
            for (int j = 0; j < 4; ++j)
                red[tt * 17 + i * 4 + j] = acc[i][j];
    }
    __syncthreads();
    if (!kh) {
        #pragma unroll
        for (int i = 0; i < 4; ++i) {
            float4 o;
            o.x = acc[i][0] + red[tt * 17 + i * 4 + 0];
            o.y = acc[i][1] + red[tt * 17 + i * 4 + 1];
            o.z = acc[i][2] + red[tt * 17 + i * 4 + 2];
            o.w = acc[i][3] + red[tt * 17 + i * 4 + 3];
            *(float4*)(Dst + (size_t)(trow * 4 + i) * Hn + n0 + tcol * 4) = o;
        }
    }
}

// ---------------------------------------------------------------------------
// Kernel 2: scores. v6: LOAD-BALANCED job decode.
// R6 counters: dur 49 us, Occupancy 5.5%, VALUBusy 17%, HBM 1.5%, conflicts
// ~0 -> not LDS, not HBM, not compute: the machine is nearly idle. Cause:
// kt was in blockIdx's LOW 6 bits, so CU c (round-robin dispatch) received
// blocks {c, c+256, c+512, c+768} which ALL share kt = c mod 64. Active iff
// kt*16 < vlen[b] -> low-kt CUs serialized 4 full jobs (~4 x 12 us = 49 us)
// while high-kt CUs did nothing.
// Fix: kt in the HIGH bits (kt = blk>>4): a CU's 4 jobs have kt spread by
// {0,16,32,48} -> per-CU active-job count is uniform (+-1) for any vlen.
// Layout/compute unchanged from v5 ([row][hq][68] conflict-free LDS,
// 8 q-rows per wave, max-free exp, atomic rowsum).
// ---------------------------------------------------------------------------
#define HQS 68          // hq quarter stride (floats): 4-bank offset
#define QRS 272         // row stride = 4 * HQS

__global__ __launch_bounds__(256) void score_kernel(
    const float* __restrict__ proj0, const float* __restrict__ proj1,
    const float* __restrict__ wv, const int* __restrict__ valid_lens,
    float* __restrict__ escores, float* __restrict__ rowsum)
{
    const int blk = blockIdx.x;             // kt*16 + b*4 + qp  (kt HIGH)
    const int qp = blk & 3;
    const int b  = (blk >> 2) & 3;
    const int kt = blk >> 4;                // 0..63
    const int vlen = valid_lens[b];
    const int k0 = kt * 16;
    if (k0 >= vlen) return;                 // fully-masked tile
    const int q0 = qp * 32;
    const int t = threadIdx.x;

    __shared__ float s_k[16 * QRS];         // 17408 B
    __shared__ float s_q[32 * QRS];         // 34816 B
    __shared__ float s_wv[QRS];             //  1088 B

    {
        const float4* k0p = (const float4*)(proj0 + ((size_t)(512 + b * Kn + k0)) * Hn);
        const float4* k1p = (const float4*)(proj1 + ((size_t)(512 + b * Kn + k0)) * Hn);
        #pragma unroll
        for (int i = 0; i < 4; ++i) {       // 16 rows x 64 float4
            int idx = t + i * 256;
            int row = idx >> 6, c4 = idx & 63;
            float4 a = k0p[idx], c = k1p[idx];
            a.x += c.x; a.y += c.y; a.z += c.z; a.w += c.w;
            *(float4*)&s_k[row * QRS + (c4 >> 4) * HQS + (c4 & 15) * 4] = a;
        }
        const float4* q0p = (const float4*)(proj0 + ((size_t)(b * Qn + q0)) * Hn);
        const float4* q1p = (const float4*)(proj1 + ((size_t)(b * Qn + q0)) * Hn);
        #pragma unroll
        for (int i = 0; i < 8; ++i) {       // 32 rows x 64 float4
            int idx = t + i * 256;
            int row = idx >> 6, c4 = idx & 63;
            float4 a = q0p[idx], c = q1p[idx];
            a.x += c.x; a.y += c.y; a.z += c.z; a.w += c.w;
            *(float4*)&s_q[row * QRS + (c4 >> 4) * HQS + (c4 & 15) * 4] = a;
        }
        if (t < 64)
            *(float4*)&s_wv[(t >> 4) * HQS + (t & 15) * 4] =
                ((const float4*)wv)[t];
    }
    __syncthreads();

    const int w = t >> 6, lane = t & 63;
    const int kloc = lane & 15, hq = lane >> 4;   // h-quarter: 64 h each
    const float4* kr = (const float4*)&s_k[kloc * QRS + hq * HQS];
    const float4* wr = (const float4*)&s_wv[hq * HQS];
    const float*  qb = &s_q[(size_t)(w * 8) * QRS + hq * HQS];

    float acc[8] = {0.f, 0.f, 0.f, 0.f, 0.f, 0.f, 0.f, 0.f};
    #pragma unroll 4
    for (int i = 0; i < 16; ++i) {          // 16 float4 = 64 h per lane
        float4 kv = kr[i];
        float4 wq = wr[i];
        #pragma unroll
        for (int qr = 0; qr < 8; ++qr) {
            float4 qv = *(const float4*)&qb[qr * QRS + i * 4];
            acc[qr] += wq.x * fast_tanh(qv.x + kv.x)
                     + wq.y * fast_tanh(qv.y + kv.y)
                     + wq.z * fast_tanh(qv.z + kv.z)
                     + wq.w * fast_tanh(qv.w + kv.w);
        }
    }
    const int k = k0 + kloc;
    #pragma unroll
    for (int qr = 0; qr < 8; ++qr) {
        float s = acc[qr];
        s += __shfl_xor(s, 16, 64);         // combine hq quarters
        s += __shfl_xor(s, 32, 64);
        float e = 0.f;
        if (lane < 16 && k < vlen) {
            e = __expf(s);
            escores[((size_t)(b * Qn + q0 + w * 8 + qr)) * Kn + k] = e;
        }
        e += __shfl_xor(e, 8, 64);
        e += __shfl_xor(e, 4, 64);
        e += __shfl_xor(e, 2, 64);
        e += __shfl_xor(e, 1, 64);
        if (lane == 0)
            atomicAdd(&rowsum[b * Qn + q0 + w * 8 + qr], e);
    }
}

// ---------------------------------------------------------------------------
// Kernel 3: AV + fused normalize. Grid 256 = b(4) x qt(8: 16 q-rows) x
// kc(8: 128 k) -> 1 block/CU: masking idles CUs but cannot serialize.
// Thread covers 2 d (float2 V loads): 16q x 2d per thread. escores staged
// with per-component k<vlen guard (masked -> 0, no escores memset);
// fully-masked chunks skip. acc * rcp(rowsum) atomically into zeroed out.
// ---------------------------------------------------------------------------
__global__ __launch_bounds__(256) void av_kernel(
    const float* __restrict__ escores, const float* __restrict__ values,
    const float* __restrict__ rowsum, const int* __restrict__ valid_lens,
    float* __restrict__ out)
{
    const int blk = blockIdx.x;         // ((b*8 + qt)*8 + kc)
    const int kc = blk & 7;
    const int qt = (blk >> 3) & 7;
    const int b  = blk >> 6;
    const int vlen = valid_lens[b];
    const int kb = kc * 128;
    if (kb >= vlen) return;             // fully-masked chunk
    const int q0 = qt * 16;
    const int t = threadIdx.x;

    __shared__ float s_e[16 * 128];     // 8 KB
    #pragma unroll
    for (int i = 0; i < 2; ++i) {       // 16 rows x 32 float4 = 512 f4
        int idx = t + i * 256;
        int row = idx >> 5, c4 = idx & 31;
        const float* esrc = escores + ((size_t)(b * Qn + q0 + row)) * Kn + kb + c4 * 4;
        int kbase = kb + c4 * 4;
        float4 ev;
        ev.x = (kbase + 0 < vlen) ? esrc[0] : 0.f;
        ev.y = (kbase + 1 < vlen) ? esrc[1] : 0.f;
        ev.z = (kbase + 2 < vlen) ? esrc[2] : 0.f;
        ev.w = (kbase + 3 < vlen) ? esrc[3] : 0.f;
        *(float4*)&s_e[row * 128 + c4 * 4] = ev;
    }
    __syncthreads();

    const int d0 = t * 2;               // 256 threads cover D=512
    const float* vb = values + ((size_t)(b * Kn + kb)) * Dn + d0;
    float accx[16], accy[16];
    #pragma unroll
    for (int j = 0; j < 16; ++j) { accx[j] = 0.f; accy[j] = 0.f; }

    #pragma unroll 2
    for (int k = 0; k < 128; k += 4) {
        float2 v0 = *(const float2*)&vb[(size_t)(k + 0) * Dn];
        float2 v1 = *(const float2*)&vb[(size_t)(k + 1) * Dn];
        float2 v2 = *(const float2*)&vb[(size_t)(k + 2) * Dn];
        float2 v3 = *(const float2*)&vb[(size_t)(k + 3) * Dn];
        #pragma unroll
        for (int j = 0; j < 16; ++j) {
            float4 e4 = *(const float4*)&s_e[j * 128 + k];  // uniform bcast
            accx[j] += e4.x * v0.x + e4.y * v1.x + e4.z * v2.x + e4.w * v3.x;
            accy[j] += e4.x * v0.y + e4.y * v1.y + e4.z * v2.y + e4.w * v3.y;
        }
    }
    float* op = out + ((size_t)(b * Qn + q0)) * Dn + d0;
    #pragma unroll
    for (int j = 0; j < 16; ++j) {
        float inv = __builtin_amdgcn_rcpf(rowsum[b * Qn + q0 + j]);
        atomicAdd(op + (size_t)j * Dn + 0, accx[j] * inv);
        atomicAdd(op + (size_t)j * Dn + 1, accy[j] * inv);
    }
}

// ---------------------------------------------------------------------------
extern "C" void kernel_launch(void* const* d_in, const int* in_sizes, int n_in,
                              void* d_out, int out_size, void* d_ws, size_t ws_size,
                              hipStream_t stream) {
    const float* queries    = (const float*)d_in[0];
    const float* keys       = (const float*)d_in[1];
    const float* values     = (const float*)d_in[2];
    const int*   valid_lens = (const int*)  d_in[3];
    const float* Wq         = (const float*)d_in[4];
    const float* Wk         = (const float*)d_in[5];
    const float* wv         = (const float*)d_in[6];
    float* out = (float*)d_out;

    // ws layout: proj partials rows 0..511 = qproj, 512..4607 = kproj
    const size_t PROJ_F = (size_t)4608 * Hn;          // 1179648 floats each
    float* proj0   = (float*)d_ws;
    float* proj1   = proj0 + PROJ_F;
    float* escores = proj1 + PROJ_F;                  // [B*Q, K] 524288 f
    float* rowsum  = escores + (size_t)Bn * Qn * Kn;  // [B*Q]       512 f

    // 3 dispatches, zero memsets (zeroing fused into proj_kernel)
    proj_kernel<<<576, 512, 0, stream>>>(queries, keys, Wq, Wk, valid_lens,
                                         proj0, proj1, rowsum, out);
    score_kernel<<<1024, 256, 0, stream>>>(proj0, proj1, wv, valid_lens,
                                           escores, rowsum);
    av_kernel<<<256, 256, 0, stream>>>(escores, values, rowsum, valid_lens,
                                       out);
}

// Round 10
// 151.588 us; speedup vs baseline: 2.5187x; 1.0416x over previous
//
#include <hip/hip_runtime.h>

#define Bn 4
#define Qn 128
#define Kn 1024
#define Dn 512   // DQ = DK = DV = 512
#define Hn 256

// tanh(x) = 1 - 2/(1 + e^{2x}).  Inf-safe: e->inf => rcp(inf)=0 => 1.
__device__ __forceinline__ float fast_tanh(float x) {
    float e = __expf(2.0f * x);
    return 1.0f - 2.0f * __builtin_amdgcn_rcpf(1.0f + e);
}

// ---------------------------------------------------------------------------
// Kernel 1: projections GEMM [4608x512]@[512x256], 64x64 tile, BK=64.
// Block-level split-K (kc in {0,1}, 256 deep, disjoint proj0/proj1 partials
// summed by consumers) + 8-wave intra-block split (waves 0-3: kk 0..31,
// waves 4-7: kk 32..63) + LDS merge. Blocks 0..127 zero `out`, block 0 zeros
// rowsum at entry (before any masked early-return) -> no memset dispatches.
// ---------------------------------------------------------------------------
#define PBK 64

__global__ __launch_bounds__(512) void proj_kernel(
    const float* __restrict__ queries, const float* __restrict__ keys,
    const float* __restrict__ Wq, const float* __restrict__ Wk,
    const int* __restrict__ valid_lens,
    float* __restrict__ proj0, float* __restrict__ proj1,
    float* __restrict__ rowsum, float* __restrict__ out)
{
    const int blk = blockIdx.x;         // ((mt*4)+nt)*2 + kc
    const int t = threadIdx.x;

    // ---- fused zeroing (must precede any early return) -------------------
    if (blk < 128) {                    // 128 blk * 512 thr * 16 B = 1 MB
        float4 z = {0.f, 0.f, 0.f, 0.f};
        ((float4*)out)[blk * 512 + t] = z;
        if (blk == 0) rowsum[t] = 0.f;  // 512 floats
    }

    const int kc = blk & 1;
    const int nt = (blk >> 1) & 3;
    const int mt = blk >> 3;            // 0..71
    const float* Asrc; const float* W;
    int m0, drow;
    if (mt < 8) {                       // query rows (512 = B*Q)
        m0 = mt * 64;
        drow = m0;
        Asrc = queries; W = Wq;
    } else {                            // key rows (4096 = B*K)
        int r0 = (mt - 8) * 64;
        int b = r0 >> 10;
        if ((r0 & 1023) >= valid_lens[b]) return;   // tile fully masked
        m0 = r0;
        drow = 512 + r0;
        Asrc = keys; W = Wk;
    }
    const int n0 = nt * 64;
    const int k0 = kc * 256;            // this block's K-chunk
    float* Dst = (kc ? proj1 : proj0) + (size_t)drow * Hn;

    __shared__ float s_a[PBK][68];      // A^T tile [k][m], pad 68 (17408 B)
    __shared__ float s_b[PBK][64];      // B tile   [k][n]   (16384 B)

    const int tt   = t & 255;           // position within k-half
    const int kh   = t >> 8;            // 0 -> kk 0..31, 1 -> kk 32..63
    const int trow = tt >> 4;           // 0..15 (x4 m)
    const int tcol = tt & 15;           // 0..15 (x4 n)
    const int kklo = kh << 5;

    const int lrow = t >> 4;            // 0..31 (staging row)
    const int lc4  = t & 15;

    float acc[4][4] = {{0.f}};
    float4 ra[2], rb[2];

    #pragma unroll
    for (int i = 0; i < 2; ++i) {       // preload kt=0
        ra[i] = *(const float4*)(Asrc + (size_t)(m0 + lrow + i * 32) * Dn + k0 + lc4 * 4);
        rb[i] = *(const float4*)(W + (size_t)(k0 + lrow + i * 32) * Hn + n0 + lc4 * 4);
    }

    for (int kt = 0; kt < 4; ++kt) {
        __syncthreads();                // prev compute done before overwrite
        #pragma unroll
        for (int i = 0; i < 2; ++i) {   // regs -> LDS (waits vmcnt here)
            int row = lrow + i * 32;
            s_a[lc4 * 4 + 0][row] = ra[i].x;
            s_a[lc4 * 4 + 1][row] = ra[i].y;
            s_a[lc4 * 4 + 2][row] = ra[i].z;
            s_a[lc4 * 4 + 3][row] = ra[i].w;
            *(float4*)&s_b[row][lc4 * 4] = rb[i];
        }
        __syncthreads();
        if (kt < 3) {                   // prefetch kt+1 (overlaps compute)
            const int d0n = k0 + (kt + 1) * PBK;
            #pragma unroll
            for (int i = 0; i < 2; ++i) {
                ra[i] = *(const float4*)(Asrc + (size_t)(m0 + lrow + i * 32) * Dn + d0n + lc4 * 4);
                rb[i] = *(const float4*)(W + (size_t)(d0n + lrow + i * 32) * Hn + n0 + lc4 * 4);
            }
        }
        #pragma unroll
        for (int kk = 0; kk < 32; ++kk) {
            float4 a4 = *(const float4*)&s_a[kklo + kk][trow * 4];
            float4 b4 = *(const float4*)&s_b[kklo + kk][tcol * 4];
            float a[4] = {a4.x, a4.y, a4.z, a4.w};
            float b[4] = {b4.x, b4.y, b4.z, b4.w};
            #pragma unroll
            for (int i = 0; i < 4; ++i)
                #pragma unroll
                for (int j = 0; j < 4; ++j)
                    acc[i][j] += a[i] * b[j];
        }
    }

    // merge the two k-halves through LDS (s_a region: 256*17 floats,
    // stride 17 keeps the scalar accesses conflict-free)
    __syncthreads();
    float* red = &s_a[0][0];
    if (kh) {
        #pragma unroll
        for (int i = 0; i < 4; ++i)
            #pragma unroll
            for (int j = 0; j < 4; ++j)
                red[tt * 17 + i * 4 + j] = acc[i][j];
    }
    __syncthreads();
    if (!kh) {
        #pragma unroll
        for (int i = 0; i < 4; ++i) {
            float4 o;
            o.x = acc[i][0] + red[tt * 17 + i * 4 + 0];
            o.y = acc[i][1] + red[tt * 17 + i * 4 + 1];
            o.z = acc[i][2] + red[tt * 17 + i * 4 + 2];
            o.w = acc[i][3] + red[tt * 17 + i * 4 + 3];
            *(float4*)(Dst + (size_t)(trow * 4 + i) * Hn + n0 + tcol * 4) = o;
        }
    }
}

// ---------------------------------------------------------------------------
// Kernel 2: scores. v7: occupancy / cold-latency tuning.
// R9 confirmed the v6 balance fix (score dropped below the 43us fill floor).
// v7 halves the q-panel: 16 q-rows per block -> grid 2048 = kt(64, HIGH
// bits) x b(4) x qp(8), LDS 35.9 KB -> 4-resident blocks/CU, 8 jobs/CU
// (~4 active after vlen masking, was ~2 of 4). Each wave handles 4 q-rows:
// K/wv fragment reuse drops 8->4 (slightly more LDS reads/element) but the
// dominant trans-pipe cost (~7 us floor) is unchanged, and cold-start
// latency + masked-tail imbalance shrink with 2x block granularity.
// Layout from v5 ([row][hq][68], conflict-free), max-free exp, atomic rowsum.
// ---------------------------------------------------------------------------
#define HQS 68          // hq quarter stride (floats): 4-bank offset
#define QRS 272         // row stride = 4 * HQS

__global__ __launch_bounds__(256) void score_kernel(
    const float* __restrict__ proj0, const float* __restrict__ proj1,
    const float* __restrict__ wv, const int* __restrict__ valid_lens,
    float* __restrict__ escores, float* __restrict__ rowsum)
{
    const int blk = blockIdx.x;             // kt*32 + b*8 + qp  (kt HIGH)
    const int qp = blk & 7;
    const int b  = (blk >> 3) & 3;
    const int kt = blk >> 5;                // 0..63
    const int vlen = valid_lens[b];
    const int k0 = kt * 16;
    if (k0 >= vlen) return;                 // fully-masked tile
    const int q0 = qp * 16;
    const int t = threadIdx.x;

    __shared__ float s_k[16 * QRS];         // 17408 B
    __shared__ float s_q[16 * QRS];         // 17408 B
    __shared__ float s_wv[QRS];             //  1088 B

    {
        const float4* k0p = (const float4*)(proj0 + ((size_t)(512 + b * Kn + k0)) * Hn);
        const float4* k1p = (const float4*)(proj1 + ((size_t)(512 + b * Kn + k0)) * Hn);
        #pragma unroll
        for (int i = 0; i < 4; ++i) {       // 16 rows x 64 float4
            int idx = t + i * 256;
            int row = idx >> 6, c4 = idx & 63;
            float4 a = k0p[idx], c = k1p[idx];
            a.x += c.x; a.y += c.y; a.z += c.z; a.w += c.w;
            *(float4*)&s_k[row * QRS + (c4 >> 4) * HQS + (c4 & 15) * 4] = a;
        }
        const float4* q0p = (const float4*)(proj0 + ((size_t)(b * Qn + q0)) * Hn);
        const float4* q1p = (const float4*)(proj1 + ((size_t)(b * Qn + q0)) * Hn);
        #pragma unroll
        for (int i = 0; i < 4; ++i) {       // 16 rows x 64 float4
            int idx = t + i * 256;
            int row = idx >> 6, c4 = idx & 63;
            float4 a = q0p[idx], c = q1p[idx];
            a.x += c.x; a.y += c.y; a.z += c.z; a.w += c.w;
            *(float4*)&s_q[row * QRS + (c4 >> 4) * HQS + (c4 & 15) * 4] = a;
        }
        if (t < 64)
            *(float4*)&s_wv[(t >> 4) * HQS + (t & 15) * 4] =
                ((const float4*)wv)[t];
    }
    __syncthreads();

    const int w = t >> 6, lane = t & 63;
    const int kloc = lane & 15, hq = lane >> 4;   // h-quarter: 64 h each
    const float4* kr = (const float4*)&s_k[kloc * QRS + hq * HQS];
    const float4* wr = (const float4*)&s_wv[hq * HQS];
    const float*  qb = &s_q[(size_t)(w * 4) * QRS + hq * HQS];

    float acc[4] = {0.f, 0.f, 0.f, 0.f};
    #pragma unroll 4
    for (int i = 0; i < 16; ++i) {          // 16 float4 = 64 h per lane
        float4 kv = kr[i];
        float4 wq = wr[i];
        #pragma unroll
        for (int qr = 0; qr < 4; ++qr) {
            float4 qv = *(const float4*)&qb[qr * QRS + i * 4];
            acc[qr] += wq.x * fast_tanh(qv.x + kv.x)
                     + wq.y * fast_tanh(qv.y + kv.y)
                     + wq.z * fast_tanh(qv.z + kv.z)
                     + wq.w * fast_tanh(qv.w + kv.w);
        }
    }
    const int k = k0 + kloc;
    #pragma unroll
    for (int qr = 0; qr < 4; ++qr) {
        float s = acc[qr];
        s += __shfl_xor(s, 16, 64);         // combine hq quarters
        s += __shfl_xor(s, 32, 64);
        float e = 0.f;
        if (lane < 16 && k < vlen) {
            e = __expf(s);
            escores[((size_t)(b * Qn + q0 + w * 4 + qr)) * Kn + k] = e;
        }
        e += __shfl_xor(e, 8, 64);
        e += __shfl_xor(e, 4, 64);
        e += __shfl_xor(e, 2, 64);
        e += __shfl_xor(e, 1, 64);
        if (lane == 0)
            atomicAdd(&rowsum[b * Qn + q0 + w * 4 + qr], e);
    }
}

// ---------------------------------------------------------------------------
// Kernel 3: AV + fused normalize. Grid 256 = b(4) x qt(8: 16 q-rows) x
// kc(8: 128 k) -> 1 block/CU: masking idles CUs but cannot serialize.
// Thread covers 2 d (float2 V loads): 16q x 2d per thread. v7: k-loop
// unroll 4 (16 V loads in flight, covers cold L3/HBM latency). escores
// staged with per-component k<vlen guard (masked -> 0, no escores memset);
// fully-masked chunks skip. acc * rcp(rowsum) atomically into zeroed out.
// ---------------------------------------------------------------------------
__global__ __launch_bounds__(256) void av_kernel(
    const float* __restrict__ escores, const float* __restrict__ values,
    const float* __restrict__ rowsum, const int* __restrict__ valid_lens,
    float* __restrict__ out)
{
    const int blk = blockIdx.x;         // ((b*8 + qt)*8 + kc)
    const int kc = blk & 7;
    const int qt = (blk >> 3) & 7;
    const int b  = blk >> 6;
    const int vlen = valid_lens[b];
    const int kb = kc * 128;
    if (kb >= vlen) return;             // fully-masked chunk
    const int q0 = qt * 16;
    const int t = threadIdx.x;

    __shared__ float s_e[16 * 128];     // 8 KB
    #pragma unroll
    for (int i = 0; i < 2; ++i) {       // 16 rows x 32 float4 = 512 f4
        int idx = t + i * 256;
        int row = idx >> 5, c4 = idx & 31;
        const float* esrc = escores + ((size_t)(b * Qn + q0 + row)) * Kn + kb + c4 * 4;
        int kbase = kb + c4 * 4;
        float4 ev;
        ev.x = (kbase + 0 < vlen) ? esrc[0] : 0.f;
        ev.y = (kbase + 1 < vlen) ? esrc[1] : 0.f;
        ev.z = (kbase + 2 < vlen) ? esrc[2] : 0.f;
        ev.w = (kbase + 3 < vlen) ? esrc[3] : 0.f;
        *(float4*)&s_e[row * 128 + c4 * 4] = ev;
    }
    __syncthreads();

    const int d0 = t * 2;               // 256 threads cover D=512
    const float* vb = values + ((size_t)(b * Kn + kb)) * Dn + d0;
    float accx[16], accy[16];
    #pragma unroll
    for (int j = 0; j < 16; ++j) { accx[j] = 0.f; accy[j] = 0.f; }

    #pragma unroll 4
    for (int k = 0; k < 128; k += 4) {
        float2 v0 = *(const float2*)&vb[(size_t)(k + 0) * Dn];
        float2 v1 = *(const float2*)&vb[(size_t)(k + 1) * Dn];
        float2 v2 = *(const float2*)&vb[(size_t)(k + 2) * Dn];
        float2 v3 = *(const float2*)&vb[(size_t)(k + 3) * Dn];
        #pragma unroll
        for (int j = 0; j < 16; ++j) {
            float4 e4 = *(const float4*)&s_e[j * 128 + k];  // uniform bcast
            accx[j] += e4.x * v0.x + e4.y * v1.x + e4.z * v2.x + e4.w * v3.x;
            accy[j] += e4.x * v0.y + e4.y * v1.y + e4.z * v2.y + e4.w * v3.y;
        }
    }
    float* op = out + ((size_t)(b * Qn + q0)) * Dn + d0;
    #pragma unroll
    for (int j = 0; j < 16; ++j) {
        float inv = __builtin_amdgcn_rcpf(rowsum[b * Qn + q0 + j]);
        atomicAdd(op + (size_t)j * Dn + 0, accx[j] * inv);
        atomicAdd(op + (size_t)j * Dn + 1, accy[j] * inv);
    }
}

// ---------------------------------------------------------------------------
extern "C" void kernel_launch(void* const* d_in, const int* in_sizes, int n_in,
                              void* d_out, int out_size, void* d_ws, size_t ws_size,
                              hipStream_t stream) {
    const float* queries    = (const float*)d_in[0];
    const float* keys       = (const float*)d_in[1];
    const float* values     = (const float*)d_in[2];
    const int*   valid_lens = (const int*)  d_in[3];
    const float* Wq         = (const float*)d_in[4];
    const float* Wk         = (const float*)d_in[5];
    const float* wv         = (const float*)d_in[6];
    float* out = (float*)d_out;

    // ws layout: proj partials rows 0..511 = qproj, 512..4607 = kproj
    const size_t PROJ_F = (size_t)4608 * Hn;          // 1179648 floats each
    float* proj0   = (float*)d_ws;
    float* proj1   = proj0 + PROJ_F;
    float* escores = proj1 + PROJ_F;                  // [B*Q, K] 524288 f
    float* rowsum  = escores + (size_t)Bn * Qn * Kn;  // [B*Q]       512 f

    // 3 dispatches, zero memsets (zeroing fused into proj_kernel)
    proj_kernel<<<576, 512, 0, stream>>>(queries, keys, Wq, Wk, valid_lens,
                                         proj0, proj1, rowsum, out);
    score_kernel<<<2048, 256, 0, stream>>>(proj0, proj1, wv, valid_lens,
                                           escores, rowsum);
    av_kernel<<<256, 256, 0, stream>>>(escores, values, rowsum, valid_lens,
                                       out);
}

// Round 11
// 144.321 us; speedup vs baseline: 2.6456x; 1.0504x over previous
//
#include <hip/hip_runtime.h>

#define Bn 4
#define Qn 128
#define Kn 1024
#define Dn 512   // DQ = DK = DV = 512
#define Hn 256

// tanh(x) = 1 - 2/(1 + e^{2x}).  Inf-safe: e->inf => rcp(inf)=0 => 1.
__device__ __forceinline__ float fast_tanh(float x) {
    float e = __expf(2.0f * x);
    return 1.0f - 2.0f * __builtin_amdgcn_rcpf(1.0f + e);
}

// ---------------------------------------------------------------------------
// Kernel 1: projections GEMM [4608x512]@[512x256], 64x64 tile, BK=64.
// Block-level split-K (kc in {0,1}, 256 deep, disjoint proj0/proj1 partials
// summed by consumers) + 8-wave intra-block split (waves 0-3: kk 0..31,
// waves 4-7: kk 32..63) + LDS merge. Blocks 0..127 zero `out`, block 0 zeros
// rowsum at entry (before any masked early-return) -> no memset dispatches.
// ---------------------------------------------------------------------------
#define PBK 64

__global__ __launch_bounds__(512) void proj_kernel(
    const float* __restrict__ queries, const float* __restrict__ keys,
    const float* __restrict__ Wq, const float* __restrict__ Wk,
    const int* __restrict__ valid_lens,
    float* __restrict__ proj0, float* __restrict__ proj1,
    float* __restrict__ rowsum, float* __restrict__ out)
{
    const int blk = blockIdx.x;         // ((mt*4)+nt)*2 + kc
    const int t = threadIdx.x;

    // ---- fused zeroing (must precede any early return) -------------------
    if (blk < 128) {                    // 128 blk * 512 thr * 16 B = 1 MB
        float4 z = {0.f, 0.f, 0.f, 0.f};
        ((float4*)out)[blk * 512 + t] = z;
        if (blk == 0) rowsum[t] = 0.f;  // 512 floats
    }

    const int kc = blk & 1;
    const int nt = (blk >> 1) & 3;
    const int mt = blk >> 3;            // 0..71
    const float* Asrc; const float* W;
    int m0, drow;
    if (mt < 8) {                       // query rows (512 = B*Q)
        m0 = mt * 64;
        drow = m0;
        Asrc = queries; W = Wq;
    } else {                            // key rows (4096 = B*K)
        int r0 = (mt - 8) * 64;
        int b = r0 >> 10;
        if ((r0 & 1023) >= valid_lens[b]) return;   // tile fully masked
        m0 = r0;
        drow = 512 + r0;
        Asrc = keys; W = Wk;
    }
    const int n0 = nt * 64;
    const int k0 = kc * 256;            // this block's K-chunk
    float* Dst = (kc ? proj1 : proj0) + (size_t)drow * Hn;

    __shared__ float s_a[PBK][68];      // A^T tile [k][m], pad 68 (17408 B)
    __shared__ float s_b[PBK][64];      // B tile   [k][n]   (16384 B)

    const int tt   = t & 255;           // position within k-half
    const int kh   = t >> 8;            // 0 -> kk 0..31, 1 -> kk 32..63
    const int trow = tt >> 4;           // 0..15 (x4 m)
    const int tcol = tt & 15;           // 0..15 (x4 n)
    const int kklo = kh << 5;

    const int lrow = t >> 4;            // 0..31 (staging row)
    const int lc4  = t & 15;

    float acc[4][4] = {{0.f}};
    float4 ra[2], rb[2];

    #pragma unroll
    for (int i = 0; i < 2; ++i) {       // preload kt=0
        ra[i] = *(const float4*)(Asrc + (size_t)(m0 + lrow + i * 32) * Dn + k0 + lc4 * 4);
        rb[i] = *(const float4*)(W + (size_t)(k0 + lrow + i * 32) * Hn + n0 + lc4 * 4);
    }

    for (int kt = 0; kt < 4; ++kt) {
        __syncthreads();                // prev compute done before overwrite
        #pragma unroll
        for (int i = 0; i < 2; ++i) {   // regs -> LDS (waits vmcnt here)
            int row = lrow + i * 32;
            s_a[lc4 * 4 + 0][row] = ra[i].x;
            s_a[lc4 * 4 + 1][row] = ra[i].y;
            s_a[lc4 * 4 + 2][row] = ra[i].z;
            s_a[lc4 * 4 + 3][row] = ra[i].w;
            *(float4*)&s_b[row][lc4 * 4] = rb[i];
        }
        __syncthreads();
        if (kt < 3) {                   // prefetch kt+1 (overlaps compute)
            const int d0n = k0 + (kt + 1) * PBK;
            #pragma unroll
            for (int i = 0; i < 2; ++i) {
                ra[i] = *(const float4*)(Asrc + (size_t)(m0 + lrow + i * 32) * Dn + d0n + lc4 * 4);
                rb[i] = *(const float4*)(W + (size_t)(d0n + lrow + i * 32) * Hn + n0 + lc4 * 4);
            }
        }
        #pragma unroll
        for (int kk = 0; kk < 32; ++kk) {
            float4 a4 = *(const float4*)&s_a[kklo + kk][trow * 4];
            float4 b4 = *(const float4*)&s_b[kklo + kk][tcol * 4];
            float a[4] = {a4.x, a4.y, a4.z, a4.w};
            float b[4] = {b4.x, b4.y, b4.z, b4.w};
            #pragma unroll
            for (int i = 0; i < 4; ++i)
                #pragma unroll
                for (int j = 0; j < 4; ++j)
                    acc[i][j] += a[i] * b[j];
        }
    }

    // merge the two k-halves through LDS (s_a region: 256*17 floats,
    // stride 17 keeps the scalar accesses conflict-free)
    __syncthreads();
    float* red = &s_a[0][0];
    if (kh) {
        #pragma unroll
        for (int i = 0; i < 4; ++i)
            #pragma unroll
            for (int j = 0; j < 4; ++j)
                red[tt * 17 + i * 4 + j] = acc[i][j];
    }
    __syncthreads();
    if (!kh) {
        #pragma unroll
        for (int i = 0; i < 4; ++i) {
            float4 o;
            o.x = acc[i][0] + red[tt * 17 + i * 4 + 0];
            o.y = acc[i][1] + red[tt * 17 + i * 4 + 1];
            o.z = acc[i][2] + red[tt * 17 + i * 4 + 2];
            o.w = acc[i][3] + red[tt * 17 + i * 4 + 3];
            *(float4*)(Dst + (size_t)(trow * 4 + i) * Hn + n0 + tcol * 4) = o;
        }
    }
}

// ---------------------------------------------------------------------------
// Kernel 2: scores. v7 (validated R10): grid 2048 = kt(64, HIGH bits) x
// b(4) x qp(8: 16 q-rows), LDS 35.9 KB -> 4 blocks/CU, balanced under vlen
// masking. Wave = 16 kloc x 4 hq, 4 q-rows/wave. [row][hq][68] conflict-free
// LDS, max-free exp (|s| <= sum|wv|), atomic rowsum.
// ---------------------------------------------------------------------------
#define HQS 68          // hq quarter stride (floats): 4-bank offset
#define QRS 272         // row stride = 4 * HQS

__global__ __launch_bounds__(256) void score_kernel(
    const float* __restrict__ proj0, const float* __restrict__ proj1,
    const float* __restrict__ wv, const int* __restrict__ valid_lens,
    float* __restrict__ escores, float* __restrict__ rowsum)
{
    const int blk = blockIdx.x;             // kt*32 + b*8 + qp  (kt HIGH)
    const int qp = blk & 7;
    const int b  = (blk >> 3) & 3;
    const int kt = blk >> 5;                // 0..63
    const int vlen = valid_lens[b];
    const int k0 = kt * 16;
    if (k0 >= vlen) return;                 // fully-masked tile
    const int q0 = qp * 16;
    const int t = threadIdx.x;

    __shared__ float s_k[16 * QRS];         // 17408 B
    __shared__ float s_q[16 * QRS];         // 17408 B
    __shared__ float s_wv[QRS];             //  1088 B

    {
        const float4* k0p = (const float4*)(proj0 + ((size_t)(512 + b * Kn + k0)) * Hn);
        const float4* k1p = (const float4*)(proj1 + ((size_t)(512 + b * Kn + k0)) * Hn);
        #pragma unroll
        for (int i = 0; i < 4; ++i) {       // 16 rows x 64 float4
            int idx = t + i * 256;
            int row = idx >> 6, c4 = idx & 63;
            float4 a = k0p[idx], c = k1p[idx];
            a.x += c.x; a.y += c.y; a.z += c.z; a.w += c.w;
            *(float4*)&s_k[row * QRS + (c4 >> 4) * HQS + (c4 & 15) * 4] = a;
        }
        const float4* q0p = (const float4*)(proj0 + ((size_t)(b * Qn + q0)) * Hn);
        const float4* q1p = (const float4*)(proj1 + ((size_t)(b * Qn + q0)) * Hn);
        #pragma unroll
        for (int i = 0; i < 4; ++i) {       // 16 rows x 64 float4
            int idx = t + i * 256;
            int row = idx >> 6, c4 = idx & 63;
            float4 a = q0p[idx], c = q1p[idx];
            a.x += c.x; a.y += c.y; a.z += c.z; a.w += c.w;
            *(float4*)&s_q[row * QRS + (c4 >> 4) * HQS + (c4 & 15) * 4] = a;
        }
        if (t < 64)
            *(float4*)&s_wv[(t >> 4) * HQS + (t & 15) * 4] =
                ((const float4*)wv)[t];
    }
    __syncthreads();

    const int w = t >> 6, lane = t & 63;
    const int kloc = lane & 15, hq = lane >> 4;   // h-quarter: 64 h each
    const float4* kr = (const float4*)&s_k[kloc * QRS + hq * HQS];
    const float4* wr = (const float4*)&s_wv[hq * HQS];
    const float*  qb = &s_q[(size_t)(w * 4) * QRS + hq * HQS];

    float acc[4] = {0.f, 0.f, 0.f, 0.f};
    #pragma unroll 4
    for (int i = 0; i < 16; ++i) {          // 16 float4 = 64 h per lane
        float4 kv = kr[i];
        float4 wq = wr[i];
        #pragma unroll
        for (int qr = 0; qr < 4; ++qr) {
            float4 qv = *(const float4*)&qb[qr * QRS + i * 4];
            acc[qr] += wq.x * fast_tanh(qv.x + kv.x)
                     + wq.y * fast_tanh(qv.y + kv.y)
                     + wq.z * fast_tanh(qv.z + kv.z)
                     + wq.w * fast_tanh(qv.w + kv.w);
        }
    }
    const int k = k0 + kloc;
    #pragma unroll
    for (int qr = 0; qr < 4; ++qr) {
        float s = acc[qr];
        s += __shfl_xor(s, 16, 64);         // combine hq quarters
        s += __shfl_xor(s, 32, 64);
        float e = 0.f;
        if (lane < 16 && k < vlen) {
            e = __expf(s);
            escores[((size_t)(b * Qn + q0 + w * 4 + qr)) * Kn + k] = e;
        }
        e += __shfl_xor(e, 8, 64);
        e += __shfl_xor(e, 4, 64);
        e += __shfl_xor(e, 2, 64);
        e += __shfl_xor(e, 1, 64);
        if (lane == 0)
            atomicAdd(&rowsum[b * Qn + q0 + w * 4 + qr], e);
    }
}

// ---------------------------------------------------------------------------
// Kernel 3: AV + fused normalize. v8: occupancy 2x for the cold path.
// R10: av ran at 1 wave/SIMD (grid 256) -> cold V-load latency fully serial.
// kc 8 -> 16 (64-k chunks): grid 512 = b(4) x qt(8: 16 q) x kc(16), i.e.
// 2 blocks/CU / 2 waves/SIMD, and each block's serial k-depth halves.
// Cost: out-atomics 2.1M -> 4.2M (~1 us L2). s_e 4 KB. escores staged with
// per-component k<vlen guard; fully-masked chunks skip. acc * rcp(rowsum)
// atomically into out (zeroed by proj).
// ---------------------------------------------------------------------------
__global__ __launch_bounds__(256) void av_kernel(
    const float* __restrict__ escores, const float* __restrict__ values,
    const float* __restrict__ rowsum, const int* __restrict__ valid_lens,
    float* __restrict__ out)
{
    const int blk = blockIdx.x;         // ((b*8 + qt)*16 + kc)
    const int kc = blk & 15;
    const int qt = (blk >> 4) & 7;
    const int b  = blk >> 7;
    const int vlen = valid_lens[b];
    const int kb = kc * 64;
    if (kb >= vlen) return;             // fully-masked chunk
    const int q0 = qt * 16;
    const int t = threadIdx.x;

    __shared__ float s_e[16 * 64];      // 4 KB
    {                                   // 16 rows x 16 float4 = 256 f4
        int row = t >> 4, c4 = t & 15;
        const float* esrc = escores + ((size_t)(b * Qn + q0 + row)) * Kn + kb + c4 * 4;
        int kbase = kb + c4 * 4;
        float4 ev;
        ev.x = (kbase + 0 < vlen) ? esrc[0] : 0.f;
        ev.y = (kbase + 1 < vlen) ? esrc[1] : 0.f;
        ev.z = (kbase + 2 < vlen) ? esrc[2] : 0.f;
        ev.w = (kbase + 3 < vlen) ? esrc[3] : 0.f;
        *(float4*)&s_e[row * 64 + c4 * 4] = ev;
    }
    __syncthreads();

    const int d0 = t * 2;               // 256 threads cover D=512
    const float* vb = values + ((size_t)(b * Kn + kb)) * Dn + d0;
    float accx[16], accy[16];
    #pragma unroll
    for (int j = 0; j < 16; ++j) { accx[j] = 0.f; accy[j] = 0.f; }

    #pragma unroll 4
    for (int k = 0; k < 64; k += 4) {
        float2 v0 = *(const float2*)&vb[(size_t)(k + 0) * Dn];
        float2 v1 = *(const float2*)&vb[(size_t)(k + 1) * Dn];
        float2 v2 = *(const float2*)&vb[(size_t)(k + 2) * Dn];
        float2 v3 = *(const float2*)&vb[(size_t)(k + 3) * Dn];
        #pragma unroll
        for (int j = 0; j < 16; ++j) {
            float4 e4 = *(const float4*)&s_e[j * 64 + k];   // uniform bcast
            accx[j] += e4.x * v0.x + e4.y * v1.x + e4.z * v2.x + e4.w * v3.x;
            accy[j] += e4.x * v0.y + e4.y * v1.y + e4.z * v2.y + e4.w * v3.y;
        }
    }
    float* op = out + ((size_t)(b * Qn + q0)) * Dn + d0;
    #pragma unroll
    for (int j = 0; j < 16; ++j) {
        float inv = __builtin_amdgcn_rcpf(rowsum[b * Qn + q0 + j]);
        atomicAdd(op + (size_t)j * Dn + 0, accx[j] * inv);
        atomicAdd(op + (size_t)j * Dn + 1, accy[j] * inv);
    }
}

// ---------------------------------------------------------------------------
extern "C" void kernel_launch(void* const* d_in, const int* in_sizes, int n_in,
                              void* d_out, int out_size, void* d_ws, size_t ws_size,
                              hipStream_t stream) {
    const float* queries    = (const float*)d_in[0];
    const float* keys       = (const float*)d_in[1];
    const float* values     = (const float*)d_in[2];
    const int*   valid_lens = (const int*)  d_in[3];
    const float* Wq         = (const float*)d_in[4];
    const float* Wk         = (const float*)d_in[5];
    const float* wv         = (const float*)d_in[6];
    float* out = (float*)d_out;

    // ws layout: proj partials rows 0..511 = qproj, 512..4607 = kproj
    const size_t PROJ_F = (size_t)4608 * Hn;          // 1179648 floats each
    float* proj0   = (float*)d_ws;
    float* proj1   = proj0 + PROJ_F;
    float* escores = proj1 + PROJ_F;                  // [B*Q, K] 524288 f
    float* rowsum  = escores + (size_t)Bn * Qn * Kn;  // [B*Q]       512 f

    // 3 dispatches, zero memsets (zeroing fused into proj_kernel)
    proj_kernel<<<576, 512, 0, stream>>>(queries, keys, Wq, Wk, valid_lens,
                                         proj0, proj1, rowsum, out);
    score_kernel<<<2048, 256, 0, stream>>>(proj0, proj1, wv, valid_lens,
                                           escores, rowsum);
    av_kernel<<<512, 256, 0, stream>>>(escores, values, rowsum, valid_lens,
                                       out);
}